// Round 6
// baseline (1230.833 us; speedup 1.0000x reference)
//
#include <hip/hip_runtime.h>
#include <hip/hip_bf16.h>
#include <cstddef>

#define HH 56
#define WW 56
#define SP 3136          // 56*56
#define CIN 64
#define COUT 256
#define NB 32
#define NEG_SLOPE 0.01f
#define TK 16

// ---------------------------------------------------------------------------
// Conv: circular 3x3, Cin=64 -> Cout=256. One block per (image,row).
// 256 threads, thread t owns cout=t for all 56 columns.
// LDS: 3 wrapped rows x 64 cin x 60 cols (16B-aligned rows) = 45 KB.
// Compute reads are wave-uniform ds_read_b128 (broadcast, conflict-free).
// ---------------------------------------------------------------------------
__global__ __launch_bounds__(256)
void conv_k(const float* __restrict__ x, const float* __restrict__ nsrc,
            const float* __restrict__ Wt, const float* __restrict__ bias,
            float* __restrict__ h1, float* __restrict__ hn)
{
    __shared__ __align__(16) float lin[3][CIN][60];
    const int row = blockIdx.x;
    const int img = blockIdx.y;
    const int tid = threadIdx.x;
    const int imgb = img & (NB - 1);
    const float* __restrict__ src = (img < NB ? x : nsrc) + (size_t)imgb * CIN * SP;
    float* __restrict__ dst = (img < NB ? h1 : hn) + (size_t)imgb * COUT * SP;

    // stage 3 input rows (row-1, row, row+1, wrapped); pad col [0] and [57]
    for (int i = tid; i < 3 * CIN * WW; i += 256) {
        int dy = i / (CIN * WW);
        int rem = i - dy * (CIN * WW);
        int ci = rem / WW;
        int col = rem - ci * WW;
        int r = row - 1 + dy;
        if (r < 0) r += HH;
        if (r >= HH) r -= HH;
        lin[dy][ci][col + 1] = src[(size_t)ci * SP + r * WW + col];
    }
    __syncthreads();
    for (int i = tid; i < 3 * CIN; i += 256) {
        int dy = i / CIN, ci = i - dy * CIN;
        lin[dy][ci][0]  = lin[dy][ci][WW];   // pad col 0 = orig col 55
        lin[dy][ci][57] = lin[dy][ci][1];    // pad col 57 = orig col 0
    }
    __syncthreads();

    const int co = tid;
    float acc[WW];
    const float bv = bias[co];
    #pragma unroll
    for (int c = 0; c < WW; ++c) acc[c] = bv;

    const float* __restrict__ wp = Wt + (size_t)co * CIN * 9;

    float w[9], wn[9];
    #pragma unroll
    for (int k = 0; k < 9; ++k) w[k] = wp[k];

    for (int ci = 0; ci < CIN; ++ci) {
        if (ci + 1 < CIN) {              // prefetch next cin's weights
            #pragma unroll
            for (int k = 0; k < 9; ++k) wn[k] = wp[(ci + 1) * 9 + k];
        }
        #pragma unroll
        for (int dy = 0; dy < 3; ++dy) {
            const float* base = &lin[dy][ci][0];
            const float w0 = w[dy * 3 + 0], w1 = w[dy * 3 + 1], w2 = w[dy * 3 + 2];
            float4 v0 = *reinterpret_cast<const float4*>(base);
            #pragma unroll
            for (int c4 = 0; c4 < 14; ++c4) {
                float4 v1 = *reinterpret_cast<const float4*>(base + 4 * c4 + 4);
                const int c = 4 * c4;
                acc[c + 0] = fmaf(v0.x, w0, fmaf(v0.y, w1, fmaf(v0.z, w2, acc[c + 0])));
                acc[c + 1] = fmaf(v0.y, w0, fmaf(v0.z, w1, fmaf(v0.w, w2, acc[c + 1])));
                acc[c + 2] = fmaf(v0.z, w0, fmaf(v0.w, w1, fmaf(v1.x, w2, acc[c + 2])));
                acc[c + 3] = fmaf(v0.w, w0, fmaf(v1.x, w1, fmaf(v1.y, w2, acc[c + 3])));
                v0 = v1;
            }
        }
        #pragma unroll
        for (int k = 0; k < 9; ++k) w[k] = wn[k];
    }

    float* op = dst + (size_t)co * SP + row * WW;
    #pragma unroll
    for (int c = 0; c < WW; c += 4) {
        *reinterpret_cast<float4*>(op + c) =
            make_float4(acc[c], acc[c + 1], acc[c + 2], acc[c + 3]);
    }
}

// ---------------------------------------------------------------------------
// a[b][n][m] = LeakyReLU( sum_f h1[b][n][f] * hn[b][m][f] )
// Tile 128(n) x 64(m), 256 blocks (full GPU). 256 threads.
// ty = tid>>3 (0..31): rows n0+4ty+i. tx = tid&7: cols {m0+4tx+w, m0+32+4tx+w}.
// LDS k-major, all fragment reads are conflict-free float4 broadcasts.
// Register double-buffer prefetch hides global latency at 1 block/CU.
// ---------------------------------------------------------------------------
__global__ __launch_bounds__(256)
void gemm_a_k(const float* __restrict__ h1, const float* __restrict__ hn,
              float* __restrict__ attn)
{
    __shared__ __align__(16) float As[TK][132];   // [k][n 0..127]
    __shared__ __align__(16) float Bs[TK][68];    // [k][m 0..63]
    const int b  = blockIdx.z;
    const int n0 = blockIdx.y * 128;
    const int m0 = blockIdx.x * 64;
    const int tid = threadIdx.x;
    const int tx = tid & 7, ty = tid >> 3;

    const float* __restrict__ A  = h1 + (size_t)b * COUT * SP;
    const float* __restrict__ Bp = hn + (size_t)b * COUT * SP;

    float acc[4][8];
    #pragma unroll
    for (int i = 0; i < 4; ++i)
        #pragma unroll
        for (int j = 0; j < 8; ++j) acc[i][j] = 0.f;

    const int ar = tid >> 2, aq = tid & 3;   // As staging: rows ar, ar+64
    const size_t aoff0 = (size_t)(n0 + ar) * SP + 4 * aq;
    const size_t aoff1 = aoff0 + (size_t)64 * SP;
    const size_t boff  = (size_t)(m0 + ar) * SP + 4 * aq;

    float4 ra0 = *reinterpret_cast<const float4*>(&A[aoff0]);
    float4 ra1 = *reinterpret_cast<const float4*>(&A[aoff1]);
    float4 rb  = *reinterpret_cast<const float4*>(&Bp[boff]);

    for (int k0 = 0; k0 < SP; k0 += TK) {
        As[4 * aq + 0][ar]      = ra0.x;
        As[4 * aq + 1][ar]      = ra0.y;
        As[4 * aq + 2][ar]      = ra0.z;
        As[4 * aq + 3][ar]      = ra0.w;
        As[4 * aq + 0][ar + 64] = ra1.x;
        As[4 * aq + 1][ar + 64] = ra1.y;
        As[4 * aq + 2][ar + 64] = ra1.z;
        As[4 * aq + 3][ar + 64] = ra1.w;
        Bs[4 * aq + 0][ar] = rb.x;
        Bs[4 * aq + 1][ar] = rb.y;
        Bs[4 * aq + 2][ar] = rb.z;
        Bs[4 * aq + 3][ar] = rb.w;
        __syncthreads();

        float4 na0 = ra0, na1 = ra1, nb = rb;
        if (k0 + TK < SP) {                       // prefetch next k-tile
            na0 = *reinterpret_cast<const float4*>(&A[aoff0 + k0 + TK]);
            na1 = *reinterpret_cast<const float4*>(&A[aoff1 + k0 + TK]);
            nb  = *reinterpret_cast<const float4*>(&Bp[boff + k0 + TK]);
        }

        #pragma unroll
        for (int kk = 0; kk < TK; ++kk) {
            float4 av = *reinterpret_cast<const float4*>(&As[kk][4 * ty]);
            float4 b0 = *reinterpret_cast<const float4*>(&Bs[kk][4 * tx]);
            float4 b1 = *reinterpret_cast<const float4*>(&Bs[kk][32 + 4 * tx]);
            const float a4[4] = {av.x, av.y, av.z, av.w};
            const float bw[8] = {b0.x, b0.y, b0.z, b0.w, b1.x, b1.y, b1.z, b1.w};
            #pragma unroll
            for (int i = 0; i < 4; ++i)
                #pragma unroll
                for (int j = 0; j < 8; ++j)
                    acc[i][j] = fmaf(a4[i], bw[j], acc[i][j]);
        }
        __syncthreads();
        ra0 = na0; ra1 = na1; rb = nb;
    }

    float* outp = attn + (size_t)b * COUT * COUT;
    #pragma unroll
    for (int i = 0; i < 4; ++i) {
        const int n = n0 + 4 * ty + i;
        float v[8];
        #pragma unroll
        for (int j = 0; j < 8; ++j) {
            float t = acc[i][j];
            v[j] = (t >= 0.f) ? t : NEG_SLOPE * t;
        }
        *reinterpret_cast<float4*>(&outp[(size_t)n * COUT + m0 + 4 * tx]) =
            make_float4(v[0], v[1], v[2], v[3]);
        *reinterpret_cast<float4*>(&outp[(size_t)n * COUT + m0 + 32 + 4 * tx]) =
            make_float4(v[4], v[5], v[6], v[7]);
    }
}

// ---------------------------------------------------------------------------
// softmax over axis n (dim=1) for each (b, m) column, in place.
// attn layout [b][n][m], m contiguous -> coalesced across threads.
// ---------------------------------------------------------------------------
__global__ __launch_bounds__(64)
void softmax_k(float* __restrict__ attn)
{
    const int b = blockIdx.y;
    const int m = blockIdx.x * 64 + threadIdx.x;
    float* a = attn + (size_t)b * COUT * COUT;
    float mx = -1e30f;
    for (int n_ = 0; n_ < COUT; ++n_) mx = fmaxf(mx, a[n_ * COUT + m]);
    float s = 0.f;
    for (int n_ = 0; n_ < COUT; ++n_) s += expf(a[n_ * COUT + m] - mx);
    float inv = 1.f / s;
    for (int n_ = 0; n_ < COUT; ++n_)
        a[n_ * COUT + m] = expf(a[n_ * COUT + m] - mx) * inv;
}

// ---------------------------------------------------------------------------
// out[b][n][f] = 0.1 * sum_m attn[b][n][m]*h1[b][m][f] + 0.9 * h1[b][n][f]
// Tile 128(n) x 128(f), K=256(m). 1600 blocks. 256 threads.
// ty = tid>>4 (0..15): rows n0+8ty+i. tx = tid&15: cols {f0+4tx+w, f0+64+4tx+w}.
// ---------------------------------------------------------------------------
__global__ __launch_bounds__(256)
void gemm_agg_k(const float* __restrict__ attn, const float* __restrict__ h1,
                float* __restrict__ out)
{
    __shared__ __align__(16) float As[TK][132];   // [m-chunk][n 0..127]
    __shared__ __align__(16) float Bs[TK][132];   // [m-chunk][f 0..127]
    const int b  = blockIdx.z;
    const int n0 = blockIdx.y * 128;
    const int f0 = blockIdx.x * 128;
    const int tid = threadIdx.x;
    const int tx = tid & 15, ty = tid >> 4;

    const float* __restrict__ A  = attn + (size_t)b * COUT * COUT;
    const float* __restrict__ Bp = h1 + (size_t)b * COUT * SP;

    float acc[8][8];
    #pragma unroll
    for (int i = 0; i < 8; ++i)
        #pragma unroll
        for (int j = 0; j < 8; ++j) acc[i][j] = 0.f;

    const int ar = tid >> 2, aq = tid & 3;    // As staging
    const int bk = tid >> 4, fq = tid & 15;   // Bs staging
    const bool f2ok = (f0 + 64) < SP;         // second f-group in range?

    for (int k0 = 0; k0 < COUT; k0 += TK) {
        float4 a0 = *reinterpret_cast<const float4*>(&A[(size_t)(n0 + ar) * COUT + k0 + 4 * aq]);
        float4 a1 = *reinterpret_cast<const float4*>(&A[(size_t)(n0 + ar + 64) * COUT + k0 + 4 * aq]);
        As[4 * aq + 0][ar]      = a0.x;
        As[4 * aq + 1][ar]      = a0.y;
        As[4 * aq + 2][ar]      = a0.z;
        As[4 * aq + 3][ar]      = a0.w;
        As[4 * aq + 0][ar + 64] = a1.x;
        As[4 * aq + 1][ar + 64] = a1.y;
        As[4 * aq + 2][ar + 64] = a1.z;
        As[4 * aq + 3][ar + 64] = a1.w;
        *reinterpret_cast<float4*>(&Bs[bk][4 * fq]) =
            *reinterpret_cast<const float4*>(&Bp[(size_t)(k0 + bk) * SP + f0 + 4 * fq]);
        if (f2ok)
            *reinterpret_cast<float4*>(&Bs[bk][64 + 4 * fq]) =
                *reinterpret_cast<const float4*>(&Bp[(size_t)(k0 + bk) * SP + f0 + 64 + 4 * fq]);
        __syncthreads();

        #pragma unroll
        for (int kk = 0; kk < TK; ++kk) {
            float4 av0 = *reinterpret_cast<const float4*>(&As[kk][8 * ty]);
            float4 av1 = *reinterpret_cast<const float4*>(&As[kk][8 * ty + 4]);
            float4 b0  = *reinterpret_cast<const float4*>(&Bs[kk][4 * tx]);
            float4 b1  = *reinterpret_cast<const float4*>(&Bs[kk][64 + 4 * tx]);
            const float a8[8] = {av0.x, av0.y, av0.z, av0.w, av1.x, av1.y, av1.z, av1.w};
            const float bw[8] = {b0.x, b0.y, b0.z, b0.w, b1.x, b1.y, b1.z, b1.w};
            #pragma unroll
            for (int i = 0; i < 8; ++i)
                #pragma unroll
                for (int j = 0; j < 8; ++j)
                    acc[i][j] = fmaf(a8[i], bw[j], acc[i][j]);
        }
        __syncthreads();
    }

    const float a1c = 1.0f - 0.9f, a9c = 0.9f;
    #pragma unroll
    for (int i = 0; i < 8; ++i) {
        const int n = n0 + 8 * ty + i;
        const float* hrow = Bp + (size_t)n * SP;
        float* orow = out + (size_t)b * COUT * SP + (size_t)n * SP;
        {
            float4 h = *reinterpret_cast<const float4*>(&hrow[f0 + 4 * tx]);
            float4 r = make_float4(a1c * acc[i][0] + a9c * h.x,
                                   a1c * acc[i][1] + a9c * h.y,
                                   a1c * acc[i][2] + a9c * h.z,
                                   a1c * acc[i][3] + a9c * h.w);
            *reinterpret_cast<float4*>(&orow[f0 + 4 * tx]) = r;
        }
        if (f2ok) {
            float4 h = *reinterpret_cast<const float4*>(&hrow[f0 + 64 + 4 * tx]);
            float4 r = make_float4(a1c * acc[i][4] + a9c * h.x,
                                   a1c * acc[i][5] + a9c * h.y,
                                   a1c * acc[i][6] + a9c * h.z,
                                   a1c * acc[i][7] + a9c * h.w);
            *reinterpret_cast<float4*>(&orow[f0 + 64 + 4 * tx]) = r;
        }
    }
}

// ---------------------------------------------------------------------------
extern "C" void kernel_launch(void* const* d_in, const int* in_sizes, int n_in,
                              void* d_out, int out_size, void* d_ws, size_t ws_size,
                              hipStream_t stream)
{
    const float* x    = (const float*)d_in[0];
    const float* nn   = (const float*)d_in[1];
    const float* W    = (const float*)d_in[2];
    const float* bias = (const float*)d_in[3];
    float* out = (float*)d_out;

    // ws layout: h1 (32*256*3136 f32 = 102.8 MB) | attn (32*256*256 f32 = 8.4 MB)
    float* h1   = (float*)d_ws;
    float* attn = (float*)((char*)d_ws + (size_t)NB * COUT * SP * sizeof(float));
    float* hn   = out;   // d_out holds hn until gemm_agg_k overwrites it

    conv_k    <<<dim3(HH, 2 * NB), 256, 0, stream>>>(x, nn, W, bias, h1, hn);
    gemm_a_k  <<<dim3(4, 2, NB),   256, 0, stream>>>(h1, hn, attn);   // 256 blocks
    softmax_k <<<dim3(4, NB),      64,  0, stream>>>(attn);
    gemm_agg_k<<<dim3(25, 2, NB),  256, 0, stream>>>(attn, h1, out);
}

// Round 8
// 786.954 us; speedup vs baseline: 1.5640x; 1.5640x over previous
//
#include <hip/hip_runtime.h>
#include <hip/hip_bf16.h>
#include <cstddef>

#define HH 56
#define WW 56
#define SP 3136          // 56*56
#define CIN 64
#define COUT 256
#define NB 32
#define NEG_SLOPE 0.01f
#define TK 16
#define PD 58            // padded spatial dim (56 + 2 circular)

typedef __attribute__((ext_vector_type(8))) short short8v;  // 8 bf16 (4 VGPRs)
typedef __attribute__((ext_vector_type(4))) float f32x4;    // MFMA accumulator

// ---------------------------------------------------------------------------
// pack_w: W[co][ci][ky][kx] f32 -> Wp_hi/Wp_lo[tap][co][ci] bf16 (hi + residual)
// ---------------------------------------------------------------------------
__global__ __launch_bounds__(256)
void pack_w(const float* __restrict__ W, ushort* __restrict__ wh, ushort* __restrict__ wl)
{
    const int id = blockIdx.x * 256 + threadIdx.x;   // 147456 = 9*256*64
    const int ci = id & 63, co = (id >> 6) & 255, tap = id >> 14;
    float v = W[(size_t)(co * 64 + ci) * 9 + tap];
    __hip_bfloat16 h = __float2bfloat16(v);
    float lo = v - __bfloat162float(h);
    __hip_bfloat16 hl = __float2bfloat16(lo);
    wh[id] = *(ushort*)&h;
    wl[id] = *(ushort*)&hl;
}

// ---------------------------------------------------------------------------
// pack_in: raw[img][ci][y][x] f32 -> in_T[img][gy][gx][ci] bf16 hi/lo, with
// circular padding built in: in_T[gy][gx] = raw[(gy-1)%56][(gx-1)%56].
// One block per (gy, img): stage the source row in LDS, transpose out.
// ---------------------------------------------------------------------------
__global__ __launch_bounds__(256)
void pack_in(const float* __restrict__ src, ushort* __restrict__ th, ushort* __restrict__ tl)
{
    __shared__ float tile[CIN][PD];
    const int gy = blockIdx.x, img = blockIdx.y, tid = threadIdx.x;
    const int sy = (gy + 55) % 56;
    {
        const int ci = tid >> 2, seg = tid & 3;
        const float* s = src + (size_t)img * CIN * SP + (size_t)ci * SP + sy * 56;
        #pragma unroll
        for (int c = 0; c < 14; ++c) tile[ci][seg * 14 + c + 1] = s[seg * 14 + c];
    }
    if (tid < 128) {
        const int ci = tid >> 1;
        const float* s2 = src + (size_t)img * CIN * SP + (size_t)ci * SP + sy * 56;
        if (tid & 1) tile[ci][PD - 1] = s2[0];
        else         tile[ci][0]      = s2[55];
    }
    __syncthreads();
    const size_t ob = ((size_t)img * PD + gy) * PD * CIN;
    for (int el = tid; el < PD * CIN; el += 256) {
        const int gx = el >> 6, ci = el & 63;
        float v = tile[ci][gx];
        __hip_bfloat16 h = __float2bfloat16(v);
        float lo = v - __bfloat162float(h);
        __hip_bfloat16 hl = __float2bfloat16(lo);
        th[ob + el] = *(ushort*)&h;     // el == gx*64 + ci
        tl[ob + el] = *(ushort*)&hl;
    }
}

// ---------------------------------------------------------------------------
// conv_mfma: implicit-GEMM 3x3 circular conv via bf16x3 MFMA.
// C[co][p] = bias[co] + sum_{tap,ci} W[co][ci][tap] * in_T[y(p)+dy][x(p)+dx][ci]
// Block: 256 thr = 4 waves; tile 128 co x 112 sp (2 output rows).
// Wave w: co [32w,32w+32) -> 2 m-frags x 7 n-frags of 16x16, K-chunks of 64 (per tap).
// 3 MFMA passes per frag pair: hi*hi + hi*lo + lo*hi (fp32 accumulate).
// ---------------------------------------------------------------------------
__global__ __launch_bounds__(256, 2)
void conv_mfma(const ushort* __restrict__ inT_hi, const ushort* __restrict__ inT_lo,
               const ushort* __restrict__ Wp_hi, const ushort* __restrict__ Wp_lo,
               const float* __restrict__ bias, float* __restrict__ dst)
{
    __shared__ __align__(16) ushort Ah[128][72];
    __shared__ __align__(16) ushort Al[128][72];
    __shared__ __align__(16) ushort Bh[112][72];
    __shared__ __align__(16) ushort Bl[112][72];
    const int tid = threadIdx.x;
    const int w = tid >> 6, l = tid & 63;
    const int co0 = blockIdx.x * 128;
    const int rp  = blockIdx.y;
    const int img = blockIdx.z;
    const int y0 = rp * 2, p0 = rp * 112;

    float* __restrict__ dimg = dst + (size_t)img * COUT * SP;   // FIX: per-image slab

    f32x4 acc[2][7];
    {
        const int rr = (l >> 4) * 4;
        #pragma unroll
        for (int m = 0; m < 2; ++m) {
            const int cb = co0 + 32 * w + 16 * m + rr;
            f32x4 bv = { bias[cb], bias[cb + 1], bias[cb + 2], bias[cb + 3] };
            #pragma unroll
            for (int nf = 0; nf < 7; ++nf) acc[m][nf] = bv;
        }
    }

    // staging assignments
    const int a_split = tid >> 7, a_row = tid & 127;
    const ushort* aW = a_split ? Wp_lo : Wp_hi;
    ushort (* __restrict__ aL)[72] = a_split ? Al : Ah;

    const int b_split = tid / 112;                // 0,1 active; 2 idle
    const int b_n = tid - b_split * 112;
    const int ry = (b_n >= 56) ? 1 : 0;
    const int xx = b_n - ry * 56;
    const ushort* bI = (b_split == 1) ? inT_lo : inT_hi;
    ushort (* __restrict__ bL)[72] = (b_split == 1) ? Bl : Bh;
    const bool bAct = tid < 224;

    for (int tap = 0; tap < 9; ++tap) {
        const int dy = tap / 3, dx = tap - dy * 3;
        {   // stage A: 128 co rows x 64 ci, both splits (16 KB)
            const uint4* g = (const uint4*)(aW + ((size_t)tap * 256 + co0 + a_row) * 64);
            uint4* d = (uint4*)&aL[a_row][0];
            #pragma unroll
            for (int j = 0; j < 8; ++j) d[j] = g[j];
        }
        if (bAct) {  // stage B: 112 spatial rows x 64 ci, both splits (14 KB)
            const int gy = y0 + ry + dy, gx = xx + dx;
            const uint4* g = (const uint4*)(bI + ((size_t)(img * PD + gy) * PD + gx) * 64);
            uint4* d = (uint4*)&bL[b_n][0];
            #pragma unroll
            for (int j = 0; j < 8; ++j) d[j] = g[j];
        }
        __syncthreads();
        #pragma unroll
        for (int ks = 0; ks < 2; ++ks) {
            const int kb = ks * 32 + (l >> 4) * 8;
            short8v ah[2], alv[2];
            #pragma unroll
            for (int m = 0; m < 2; ++m) {
                const int row = 32 * w + 16 * m + (l & 15);
                ah[m]  = *(const short8v*)&Ah[row][kb];
                alv[m] = *(const short8v*)&Al[row][kb];
            }
            #pragma unroll
            for (int nf = 0; nf < 7; ++nf) {
                const int brow = nf * 16 + (l & 15);
                short8v bh  = *(const short8v*)&Bh[brow][kb];
                short8v blv = *(const short8v*)&Bl[brow][kb];
                #pragma unroll
                for (int m = 0; m < 2; ++m) {
                    acc[m][nf] = __builtin_amdgcn_mfma_f32_16x16x32_bf16(ah[m],  bh,  acc[m][nf], 0, 0, 0);
                    acc[m][nf] = __builtin_amdgcn_mfma_f32_16x16x32_bf16(ah[m],  blv, acc[m][nf], 0, 0, 0);
                    acc[m][nf] = __builtin_amdgcn_mfma_f32_16x16x32_bf16(alv[m], bh,  acc[m][nf], 0, 0, 0);
                }
            }
        }
        __syncthreads();
    }

    // epilogue: D row=(l>>4)*4+r -> co, col=l&15 -> p (verified layout, m89)
    const int rr = (l >> 4) * 4, cc = l & 15;
    #pragma unroll
    for (int m = 0; m < 2; ++m) {
        const int cb = co0 + 32 * w + 16 * m + rr;
        #pragma unroll
        for (int nf = 0; nf < 7; ++nf) {
            const int p = p0 + nf * 16 + cc;
            #pragma unroll
            for (int r = 0; r < 4; ++r)
                dimg[(size_t)(cb + r) * SP + p] = acc[m][nf][r];
        }
    }
}

// ---------------------------------------------------------------------------
// a[b][n][m] = LeakyReLU( sum_f h1[b][n][f] * hn[b][m][f] )  (unchanged)
// ---------------------------------------------------------------------------
__global__ __launch_bounds__(256)
void gemm_a_k(const float* __restrict__ h1, const float* __restrict__ hn,
              float* __restrict__ attn)
{
    __shared__ __align__(16) float As[TK][132];
    __shared__ __align__(16) float Bs[TK][68];
    const int b  = blockIdx.z;
    const int n0 = blockIdx.y * 128;
    const int m0 = blockIdx.x * 64;
    const int tid = threadIdx.x;
    const int tx = tid & 7, ty = tid >> 3;

    const float* __restrict__ A  = h1 + (size_t)b * COUT * SP;
    const float* __restrict__ Bp = hn + (size_t)b * COUT * SP;

    float acc[4][8];
    #pragma unroll
    for (int i = 0; i < 4; ++i)
        #pragma unroll
        for (int j = 0; j < 8; ++j) acc[i][j] = 0.f;

    const int ar = tid >> 2, aq = tid & 3;
    const size_t aoff0 = (size_t)(n0 + ar) * SP + 4 * aq;
    const size_t aoff1 = aoff0 + (size_t)64 * SP;
    const size_t boff  = (size_t)(m0 + ar) * SP + 4 * aq;

    float4 ra0 = *reinterpret_cast<const float4*>(&A[aoff0]);
    float4 ra1 = *reinterpret_cast<const float4*>(&A[aoff1]);
    float4 rb  = *reinterpret_cast<const float4*>(&Bp[boff]);

    for (int k0 = 0; k0 < SP; k0 += TK) {
        As[4 * aq + 0][ar]      = ra0.x;
        As[4 * aq + 1][ar]      = ra0.y;
        As[4 * aq + 2][ar]      = ra0.z;
        As[4 * aq + 3][ar]      = ra0.w;
        As[4 * aq + 0][ar + 64] = ra1.x;
        As[4 * aq + 1][ar + 64] = ra1.y;
        As[4 * aq + 2][ar + 64] = ra1.z;
        As[4 * aq + 3][ar + 64] = ra1.w;
        Bs[4 * aq + 0][ar] = rb.x;
        Bs[4 * aq + 1][ar] = rb.y;
        Bs[4 * aq + 2][ar] = rb.z;
        Bs[4 * aq + 3][ar] = rb.w;
        __syncthreads();

        float4 na0 = ra0, na1 = ra1, nb = rb;
        if (k0 + TK < SP) {
            na0 = *reinterpret_cast<const float4*>(&A[aoff0 + k0 + TK]);
            na1 = *reinterpret_cast<const float4*>(&A[aoff1 + k0 + TK]);
            nb  = *reinterpret_cast<const float4*>(&Bp[boff + k0 + TK]);
        }

        #pragma unroll
        for (int kk = 0; kk < TK; ++kk) {
            float4 av = *reinterpret_cast<const float4*>(&As[kk][4 * ty]);
            float4 b0 = *reinterpret_cast<const float4*>(&Bs[kk][4 * tx]);
            float4 b1 = *reinterpret_cast<const float4*>(&Bs[kk][32 + 4 * tx]);
            const float a4[4] = {av.x, av.y, av.z, av.w};
            const float bw[8] = {b0.x, b0.y, b0.z, b0.w, b1.x, b1.y, b1.z, b1.w};
            #pragma unroll
            for (int i = 0; i < 4; ++i)
                #pragma unroll
                for (int j = 0; j < 8; ++j)
                    acc[i][j] = fmaf(a4[i], bw[j], acc[i][j]);
        }
        __syncthreads();
        ra0 = na0; ra1 = na1; rb = nb;
    }

    float* outp = attn + (size_t)b * COUT * COUT;
    #pragma unroll
    for (int i = 0; i < 4; ++i) {
        const int n = n0 + 4 * ty + i;
        float v[8];
        #pragma unroll
        for (int j = 0; j < 8; ++j) {
            float t = acc[i][j];
            v[j] = (t >= 0.f) ? t : NEG_SLOPE * t;
        }
        *reinterpret_cast<float4*>(&outp[(size_t)n * COUT + m0 + 4 * tx]) =
            make_float4(v[0], v[1], v[2], v[3]);
        *reinterpret_cast<float4*>(&outp[(size_t)n * COUT + m0 + 32 + 4 * tx]) =
            make_float4(v[4], v[5], v[6], v[7]);
    }
}

// ---------------------------------------------------------------------------
// softmax over axis n (dim=1) per (b,m) column, in place. (unchanged)
// ---------------------------------------------------------------------------
__global__ __launch_bounds__(64)
void softmax_k(float* __restrict__ attn)
{
    const int b = blockIdx.y;
    const int m = blockIdx.x * 64 + threadIdx.x;
    float* a = attn + (size_t)b * COUT * COUT;
    float mx = -1e30f;
    for (int n_ = 0; n_ < COUT; ++n_) mx = fmaxf(mx, a[n_ * COUT + m]);
    float s = 0.f;
    for (int n_ = 0; n_ < COUT; ++n_) s += expf(a[n_ * COUT + m] - mx);
    float inv = 1.f / s;
    for (int n_ = 0; n_ < COUT; ++n_)
        a[n_ * COUT + m] = expf(a[n_ * COUT + m] - mx) * inv;
}

// ---------------------------------------------------------------------------
// out = 0.1 * attn@h1 + 0.9 * h1  (unchanged)
// ---------------------------------------------------------------------------
__global__ __launch_bounds__(256)
void gemm_agg_k(const float* __restrict__ attn, const float* __restrict__ h1,
                float* __restrict__ out)
{
    __shared__ __align__(16) float As[TK][132];
    __shared__ __align__(16) float Bs[TK][132];
    const int b  = blockIdx.z;
    const int n0 = blockIdx.y * 128;
    const int f0 = blockIdx.x * 128;
    const int tid = threadIdx.x;
    const int tx = tid & 15, ty = tid >> 4;

    const float* __restrict__ A  = attn + (size_t)b * COUT * COUT;
    const float* __restrict__ Bp = h1 + (size_t)b * COUT * SP;

    float acc[8][8];
    #pragma unroll
    for (int i = 0; i < 8; ++i)
        #pragma unroll
        for (int j = 0; j < 8; ++j) acc[i][j] = 0.f;

    const int ar = tid >> 2, aq = tid & 3;
    const int bk = tid >> 4, fq = tid & 15;
    const bool f2ok = (f0 + 64) < SP;

    for (int k0 = 0; k0 < COUT; k0 += TK) {
        float4 a0 = *reinterpret_cast<const float4*>(&A[(size_t)(n0 + ar) * COUT + k0 + 4 * aq]);
        float4 a1 = *reinterpret_cast<const float4*>(&A[(size_t)(n0 + ar + 64) * COUT + k0 + 4 * aq]);
        As[4 * aq + 0][ar]      = a0.x;
        As[4 * aq + 1][ar]      = a0.y;
        As[4 * aq + 2][ar]      = a0.z;
        As[4 * aq + 3][ar]      = a0.w;
        As[4 * aq + 0][ar + 64] = a1.x;
        As[4 * aq + 1][ar + 64] = a1.y;
        As[4 * aq + 2][ar + 64] = a1.z;
        As[4 * aq + 3][ar + 64] = a1.w;
        *reinterpret_cast<float4*>(&Bs[bk][4 * fq]) =
            *reinterpret_cast<const float4*>(&Bp[(size_t)(k0 + bk) * SP + f0 + 4 * fq]);
        if (f2ok)
            *reinterpret_cast<float4*>(&Bs[bk][64 + 4 * fq]) =
                *reinterpret_cast<const float4*>(&Bp[(size_t)(k0 + bk) * SP + f0 + 64 + 4 * fq]);
        __syncthreads();

        #pragma unroll
        for (int kk = 0; kk < TK; ++kk) {
            float4 av0 = *reinterpret_cast<const float4*>(&As[kk][8 * ty]);
            float4 av1 = *reinterpret_cast<const float4*>(&As[kk][8 * ty + 4]);
            float4 b0  = *reinterpret_cast<const float4*>(&Bs[kk][4 * tx]);
            float4 b1  = *reinterpret_cast<const float4*>(&Bs[kk][64 + 4 * tx]);
            const float a8[8] = {av0.x, av0.y, av0.z, av0.w, av1.x, av1.y, av1.z, av1.w};
            const float bw[8] = {b0.x, b0.y, b0.z, b0.w, b1.x, b1.y, b1.z, b1.w};
            #pragma unroll
            for (int i = 0; i < 8; ++i)
                #pragma unroll
                for (int j = 0; j < 8; ++j)
                    acc[i][j] = fmaf(a8[i], bw[j], acc[i][j]);
        }
        __syncthreads();
    }

    const float a1c = 1.0f - 0.9f, a9c = 0.9f;
    #pragma unroll
    for (int i = 0; i < 8; ++i) {
        const int n = n0 + 8 * ty + i;
        const float* hrow = Bp + (size_t)n * SP;
        float* orow = out + (size_t)b * COUT * SP + (size_t)n * SP;
        {
            float4 h = *reinterpret_cast<const float4*>(&hrow[f0 + 4 * tx]);
            float4 r = make_float4(a1c * acc[i][0] + a9c * h.x,
                                   a1c * acc[i][1] + a9c * h.y,
                                   a1c * acc[i][2] + a9c * h.z,
                                   a1c * acc[i][3] + a9c * h.w);
            *reinterpret_cast<float4*>(&orow[f0 + 4 * tx]) = r;
        }
        if (f2ok) {
            float4 h = *reinterpret_cast<const float4*>(&hrow[f0 + 64 + 4 * tx]);
            float4 r = make_float4(a1c * acc[i][4] + a9c * h.x,
                                   a1c * acc[i][5] + a9c * h.y,
                                   a1c * acc[i][6] + a9c * h.z,
                                   a1c * acc[i][7] + a9c * h.w);
            *reinterpret_cast<float4*>(&orow[f0 + 64 + 4 * tx]) = r;
        }
    }
}

// ---------------------------------------------------------------------------
extern "C" void kernel_launch(void* const* d_in, const int* in_sizes, int n_in,
                              void* d_out, int out_size, void* d_ws, size_t ws_size,
                              hipStream_t stream)
{
    const float* x    = (const float*)d_in[0];
    const float* nn   = (const float*)d_in[1];
    const float* W    = (const float*)d_in[2];
    const float* bias = (const float*)d_in[3];
    float* out = (float*)d_out;

    // ws layout: h1 (102.8 MB) | zone (8.39 MB): conv phase -> inT(6.89)+Wp(0.59);
    // gemm phase -> attn (8.39, overwrites inT/Wp after convs complete).
    float*  h1     = (float*)d_ws;
    char*   zone   = (char*)d_ws + (size_t)NB * COUT * SP * sizeof(float);
    ushort* inT_hi = (ushort*)zone;
    ushort* inT_lo = inT_hi + (size_t)8 * PD * PD * CIN;       // 8 imgs/chunk
    ushort* Wp_hi  = inT_lo + (size_t)8 * PD * PD * CIN;
    ushort* Wp_lo  = Wp_hi + 9 * 256 * 64;
    float*  attn   = (float*)zone;
    float*  hnp    = out;   // d_out holds hn until gemm_agg_k overwrites it

    pack_w<<<576, 256, 0, stream>>>(W, Wp_hi, Wp_lo);

    for (int c = 0; c < 8; ++c) {   // 4 chunks of x -> h1, 4 chunks of n -> hn
        const float* src = (c < 4) ? x  + (size_t)(8 * c)      * CIN * SP
                                   : nn + (size_t)(8 * c - 32) * CIN * SP;
        float*       dst = (c < 4) ? h1  + (size_t)(8 * c)      * COUT * SP
                                   : hnp + (size_t)(8 * c - 32) * COUT * SP;
        pack_in  <<<dim3(PD, 8),   256, 0, stream>>>(src, inT_hi, inT_lo);
        conv_mfma<<<dim3(2, 28, 8), 256, 0, stream>>>(inT_hi, inT_lo, Wp_hi, Wp_lo, bias, dst);
    }

    gemm_a_k  <<<dim3(4, 2, NB),  256, 0, stream>>>(h1, hnp, attn);
    softmax_k <<<dim3(4, NB),     64,  0, stream>>>(attn);
    gemm_agg_k<<<dim3(25, 2, NB), 256, 0, stream>>>(attn, h1, out);
}

// Round 9
// 703.978 us; speedup vs baseline: 1.7484x; 1.1179x over previous
//
#include <hip/hip_runtime.h>
#include <hip/hip_bf16.h>
#include <cstddef>

#define HH 56
#define WW 56
#define SP 3136          // 56*56
#define CIN 64
#define COUT 256
#define NB 32
#define NEG_SLOPE 0.01f
#define TK 16
#define PD 58            // padded spatial dim (56 + 2 circular)

typedef __attribute__((ext_vector_type(8))) short short8v;  // 8 bf16 (4 VGPRs)
typedef __attribute__((ext_vector_type(4))) float f32x4;    // MFMA accumulator

__device__ __forceinline__ float bfr(ushort h) {
    union { uint u; float f; } c; c.u = ((uint)h) << 16; return c.f;
}
__device__ __forceinline__ void split_bf(float v, ushort& hi, ushort& lo) {
    __hip_bfloat16 h = __float2bfloat16(v);
    float r = v - __bfloat162float(h);
    __hip_bfloat16 l2 = __float2bfloat16(r);
    hi = *(ushort*)&h; lo = *(ushort*)&l2;
}

// ---------------------------------------------------------------------------
// pack_w: W[co][ci][ky][kx] f32 -> Wp_hi/Wp_lo[tap][co][ci] bf16 (hi + residual)
// ---------------------------------------------------------------------------
__global__ __launch_bounds__(256)
void pack_w(const float* __restrict__ W, ushort* __restrict__ wh, ushort* __restrict__ wl)
{
    const int id = blockIdx.x * 256 + threadIdx.x;   // 147456 = 9*256*64
    const int ci = id & 63, co = (id >> 6) & 255, tap = id >> 14;
    float v = W[(size_t)(co * 64 + ci) * 9 + tap];
    ushort hi, lo; split_bf(v, hi, lo);
    wh[id] = hi; wl[id] = lo;
}

// ---------------------------------------------------------------------------
// pack_in: raw[img][ci][y][x] f32 -> in_T[img][gy][gx][ci] bf16 hi/lo, with
// circular padding built in: in_T[gy][gx] = raw[(gy-1)%56][(gx-1)%56].
// ---------------------------------------------------------------------------
__global__ __launch_bounds__(256)
void pack_in(const float* __restrict__ src, ushort* __restrict__ th, ushort* __restrict__ tl)
{
    __shared__ float tile[CIN][PD];
    const int gy = blockIdx.x, img = blockIdx.y, tid = threadIdx.x;
    const int sy = (gy + 55) % 56;
    {
        const int ci = tid >> 2, seg = tid & 3;
        const float* s = src + (size_t)img * CIN * SP + (size_t)ci * SP + sy * 56;
        #pragma unroll
        for (int c = 0; c < 14; ++c) tile[ci][seg * 14 + c + 1] = s[seg * 14 + c];
    }
    if (tid < 128) {
        const int ci = tid >> 1;
        const float* s2 = src + (size_t)img * CIN * SP + (size_t)ci * SP + sy * 56;
        if (tid & 1) tile[ci][PD - 1] = s2[0];
        else         tile[ci][0]      = s2[55];
    }
    __syncthreads();
    const size_t ob = ((size_t)img * PD + gy) * PD * CIN;
    for (int el = tid; el < PD * CIN; el += 256) {
        const int gx = el >> 6, ci = el & 63;
        float v = tile[ci][gx];
        ushort hi, lo; split_bf(v, hi, lo);
        th[ob + el] = hi;     // el == gx*64 + ci
        tl[ob + el] = lo;
    }
}

// ---------------------------------------------------------------------------
// conv_mfma: implicit-GEMM 3x3 circular conv via bf16x3 MFMA.
// Epilogue now writes bf16 hi/lo split planes (dh/dl) instead of f32.
// ---------------------------------------------------------------------------
__global__ __launch_bounds__(256, 2)
void conv_mfma(const ushort* __restrict__ inT_hi, const ushort* __restrict__ inT_lo,
               const ushort* __restrict__ Wp_hi, const ushort* __restrict__ Wp_lo,
               const float* __restrict__ bias,
               ushort* __restrict__ dsth, ushort* __restrict__ dstl)
{
    __shared__ __align__(16) ushort Ah[128][72];
    __shared__ __align__(16) ushort Al[128][72];
    __shared__ __align__(16) ushort Bh[112][72];
    __shared__ __align__(16) ushort Bl[112][72];
    const int tid = threadIdx.x;
    const int w = tid >> 6, l = tid & 63;
    const int co0 = blockIdx.x * 128;
    const int rp  = blockIdx.y;
    const int img = blockIdx.z;
    const int y0 = rp * 2, p0 = rp * 112;

    ushort* __restrict__ dh = dsth + (size_t)img * COUT * SP;
    ushort* __restrict__ dl = dstl + (size_t)img * COUT * SP;

    f32x4 acc[2][7];
    {
        const int rr = (l >> 4) * 4;
        #pragma unroll
        for (int m = 0; m < 2; ++m) {
            const int cb = co0 + 32 * w + 16 * m + rr;
            f32x4 bv = { bias[cb], bias[cb + 1], bias[cb + 2], bias[cb + 3] };
            #pragma unroll
            for (int nf = 0; nf < 7; ++nf) acc[m][nf] = bv;
        }
    }

    const int a_split = tid >> 7, a_row = tid & 127;
    const ushort* aW = a_split ? Wp_lo : Wp_hi;
    ushort (* __restrict__ aL)[72] = a_split ? Al : Ah;

    const int b_split = tid / 112;                // 0,1 active; 2 idle
    const int b_n = tid - b_split * 112;
    const int ry = (b_n >= 56) ? 1 : 0;
    const int xx = b_n - ry * 56;
    const ushort* bI = (b_split == 1) ? inT_lo : inT_hi;
    ushort (* __restrict__ bL)[72] = (b_split == 1) ? Bl : Bh;
    const bool bAct = tid < 224;

    for (int tap = 0; tap < 9; ++tap) {
        const int dy = tap / 3, dx = tap - dy * 3;
        {
            const uint4* g = (const uint4*)(aW + ((size_t)tap * 256 + co0 + a_row) * 64);
            uint4* d = (uint4*)&aL[a_row][0];
            #pragma unroll
            for (int j = 0; j < 8; ++j) d[j] = g[j];
        }
        if (bAct) {
            const int gy = y0 + ry + dy, gx = xx + dx;
            const uint4* g = (const uint4*)(bI + ((size_t)(img * PD + gy) * PD + gx) * 64);
            uint4* d = (uint4*)&bL[b_n][0];
            #pragma unroll
            for (int j = 0; j < 8; ++j) d[j] = g[j];
        }
        __syncthreads();
        #pragma unroll
        for (int ks = 0; ks < 2; ++ks) {
            const int kb = ks * 32 + (l >> 4) * 8;
            short8v ah[2], alv[2];
            #pragma unroll
            for (int m = 0; m < 2; ++m) {
                const int row = 32 * w + 16 * m + (l & 15);
                ah[m]  = *(const short8v*)&Ah[row][kb];
                alv[m] = *(const short8v*)&Al[row][kb];
            }
            #pragma unroll
            for (int nf = 0; nf < 7; ++nf) {
                const int brow = nf * 16 + (l & 15);
                short8v bh  = *(const short8v*)&Bh[brow][kb];
                short8v blv = *(const short8v*)&Bl[brow][kb];
                #pragma unroll
                for (int m = 0; m < 2; ++m) {
                    acc[m][nf] = __builtin_amdgcn_mfma_f32_16x16x32_bf16(ah[m],  bh,  acc[m][nf], 0, 0, 0);
                    acc[m][nf] = __builtin_amdgcn_mfma_f32_16x16x32_bf16(ah[m],  blv, acc[m][nf], 0, 0, 0);
                    acc[m][nf] = __builtin_amdgcn_mfma_f32_16x16x32_bf16(alv[m], bh,  acc[m][nf], 0, 0, 0);
                }
            }
        }
        __syncthreads();
    }

    const int rr = (l >> 4) * 4, cc = l & 15;
    #pragma unroll
    for (int m = 0; m < 2; ++m) {
        const int cb = co0 + 32 * w + 16 * m + rr;
        #pragma unroll
        for (int nf = 0; nf < 7; ++nf) {
            const int p = p0 + nf * 16 + cc;
            #pragma unroll
            for (int r = 0; r < 4; ++r) {
                ushort hi, lo; split_bf(acc[m][nf][r], hi, lo);
                dh[(size_t)(cb + r) * SP + p] = hi;
                dl[(size_t)(cb + r) * SP + p] = lo;
            }
        }
    }
}

// ---------------------------------------------------------------------------
// gemm_a_mfma: a[b][n][m] = LeakyReLU( sum_k h1[n,k]*hn[m,k] ), bf16x3 MFMA.
// Tile 128n x 64m, 4 waves; wave w: n rows [32w,32w+32) x all 64 m.
// grid (img=32, tile=8): XCD k (id%8) gets img==k mod 8 -> 4 imgs/XCD, L2 reuse.
// ---------------------------------------------------------------------------
__global__ __launch_bounds__(256)
void gemm_a_mfma(const ushort* __restrict__ h1h, const ushort* __restrict__ h1l,
                 const ushort* __restrict__ hnh, const ushort* __restrict__ hnl,
                 float* __restrict__ attn)
{
    __shared__ __align__(16) ushort Ah[128][72];
    __shared__ __align__(16) ushort Al[128][72];
    __shared__ __align__(16) ushort Bh[64][72];
    __shared__ __align__(16) ushort Bl[64][72];
    const int tid = threadIdx.x, w = tid >> 6, l = tid & 63;
    const int img = blockIdx.x, tile = blockIdx.y;
    const int n0 = (tile & 1) * 128, m0 = (tile >> 1) * 64;

    const ushort* __restrict__ Ahg = h1h + ((size_t)img * COUT + n0) * SP;
    const ushort* __restrict__ Alg = h1l + ((size_t)img * COUT + n0) * SP;
    const ushort* __restrict__ Bhg = hnh + ((size_t)img * COUT + m0) * SP;
    const ushort* __restrict__ Blg = hnl + ((size_t)img * COUT + m0) * SP;

    f32x4 acc[2][4];
    #pragma unroll
    for (int nf = 0; nf < 2; ++nf)
        #pragma unroll
        for (int mf = 0; mf < 4; ++mf) acc[nf][mf] = (f32x4){0.f, 0.f, 0.f, 0.f};

    const int arow = tid >> 1, ac = (tid & 1) * 32;          // A: 128 rows x 2 halves
    const int brow = tid >> 2, bq = tid & 3;                 // B: 64 rows x 4 pieces
    const int bpl = bq >> 1, bc = (bq & 1) * 32;
    const ushort* __restrict__ Bsrc = bpl ? Blg : Bhg;
    ushort (* __restrict__ Bdst)[72] = bpl ? Bl : Bh;

    for (int k0 = 0; k0 < SP; k0 += 64) {
        {
            const uint4* g0 = (const uint4*)(Ahg + (size_t)arow * SP + k0 + ac);
            const uint4* g1 = (const uint4*)(Alg + (size_t)arow * SP + k0 + ac);
            uint4* d0 = (uint4*)&Ah[arow][ac];
            uint4* d1 = (uint4*)&Al[arow][ac];
            #pragma unroll
            for (int j = 0; j < 4; ++j) { d0[j] = g0[j]; d1[j] = g1[j]; }
        }
        {
            const uint4* g = (const uint4*)(Bsrc + (size_t)brow * SP + k0 + bc);
            uint4* d = (uint4*)&Bdst[brow][bc];
            #pragma unroll
            for (int j = 0; j < 4; ++j) d[j] = g[j];
        }
        __syncthreads();
        #pragma unroll
        for (int ks = 0; ks < 2; ++ks) {
            const int kb = ks * 32 + (l >> 4) * 8;
            short8v ah[2], alv[2];
            #pragma unroll
            for (int nf = 0; nf < 2; ++nf) {
                const int row = 32 * w + 16 * nf + (l & 15);
                ah[nf]  = *(const short8v*)&Ah[row][kb];
                alv[nf] = *(const short8v*)&Al[row][kb];
            }
            #pragma unroll
            for (int mf = 0; mf < 4; ++mf) {
                const int br = mf * 16 + (l & 15);
                short8v bh  = *(const short8v*)&Bh[br][kb];
                short8v blv = *(const short8v*)&Bl[br][kb];
                #pragma unroll
                for (int nf = 0; nf < 2; ++nf) {
                    acc[nf][mf] = __builtin_amdgcn_mfma_f32_16x16x32_bf16(ah[nf],  bh,  acc[nf][mf], 0, 0, 0);
                    acc[nf][mf] = __builtin_amdgcn_mfma_f32_16x16x32_bf16(ah[nf],  blv, acc[nf][mf], 0, 0, 0);
                    acc[nf][mf] = __builtin_amdgcn_mfma_f32_16x16x32_bf16(alv[nf], bh,  acc[nf][mf], 0, 0, 0);
                }
            }
        }
        __syncthreads();
    }

    const int rr = (l >> 4) * 4, cc = l & 15;
    float* __restrict__ aimg = attn + (size_t)img * COUT * COUT;
    #pragma unroll
    for (int nf = 0; nf < 2; ++nf) {
        const int nb = n0 + 32 * w + 16 * nf + rr;
        #pragma unroll
        for (int mf = 0; mf < 4; ++mf) {
            const int m = m0 + 16 * mf + cc;
            #pragma unroll
            for (int r = 0; r < 4; ++r) {
                float v = acc[nf][mf][r];
                v = (v >= 0.f) ? v : NEG_SLOPE * v;
                aimg[(size_t)(nb + r) * COUT + m] = v;
            }
        }
    }
}

// ---------------------------------------------------------------------------
// softmax over axis n (dim=1) per (b,m) column, in place. (unchanged)
// ---------------------------------------------------------------------------
__global__ __launch_bounds__(64)
void softmax_k(float* __restrict__ attn)
{
    const int b = blockIdx.y;
    const int m = blockIdx.x * 64 + threadIdx.x;
    float* a = attn + (size_t)b * COUT * COUT;
    float mx = -1e30f;
    for (int n_ = 0; n_ < COUT; ++n_) mx = fmaxf(mx, a[n_ * COUT + m]);
    float s = 0.f;
    for (int n_ = 0; n_ < COUT; ++n_) s += expf(a[n_ * COUT + m] - mx);
    float inv = 1.f / s;
    for (int n_ = 0; n_ < COUT; ++n_)
        a[n_ * COUT + m] = expf(a[n_ * COUT + m] - mx) * inv;
}

// ---------------------------------------------------------------------------
// out[b][n][f] = 0.1 * sum_m attn[n][m]*h1[m][f] + 0.9 * h1[n][f]
// fp32 VALU compute; h1 reconstructed from bf16 hi/lo planes.
// ---------------------------------------------------------------------------
__global__ __launch_bounds__(256)
void gemm_agg_k(const float* __restrict__ attn,
                const ushort* __restrict__ h1h, const ushort* __restrict__ h1l,
                float* __restrict__ out)
{
    __shared__ __align__(16) float As[TK][132];   // [m-chunk][n 0..127]
    __shared__ __align__(16) float Bs[TK][132];   // [m-chunk][f 0..127]
    const int b  = blockIdx.z;
    const int n0 = blockIdx.y * 128;
    const int f0 = blockIdx.x * 128;
    const int tid = threadIdx.x;
    const int tx = tid & 15, ty = tid >> 4;

    const float*  __restrict__ A  = attn + (size_t)b * COUT * COUT;
    const ushort* __restrict__ Hh = h1h + (size_t)b * COUT * SP;
    const ushort* __restrict__ Hl = h1l + (size_t)b * COUT * SP;

    float acc[8][8];
    #pragma unroll
    for (int i = 0; i < 8; ++i)
        #pragma unroll
        for (int j = 0; j < 8; ++j) acc[i][j] = 0.f;

    const int ar = tid >> 2, aq = tid & 3;    // As staging
    const int bk = tid >> 4, fq = tid & 15;   // Bs staging (8 f per thread)
    const bool f2ok = (f0 + 64) < SP;

    for (int k0 = 0; k0 < COUT; k0 += TK) {
        float4 a0 = *reinterpret_cast<const float4*>(&A[(size_t)(n0 + ar) * COUT + k0 + 4 * aq]);
        float4 a1 = *reinterpret_cast<const float4*>(&A[(size_t)(n0 + ar + 64) * COUT + k0 + 4 * aq]);
        As[4 * aq + 0][ar]      = a0.x;
        As[4 * aq + 1][ar]      = a0.y;
        As[4 * aq + 2][ar]      = a0.z;
        As[4 * aq + 3][ar]      = a0.w;
        As[4 * aq + 0][ar + 64] = a1.x;
        As[4 * aq + 1][ar + 64] = a1.y;
        As[4 * aq + 2][ar + 64] = a1.z;
        As[4 * aq + 3][ar + 64] = a1.w;
        {
            const int f = f0 + 8 * fq;
            float4 r0, r1;
            if (f + 7 < SP) {
                uint4 hh = *(const uint4*)&Hh[(size_t)(k0 + bk) * SP + f];
                uint4 hl = *(const uint4*)&Hl[(size_t)(k0 + bk) * SP + f];
                const ushort* hp = (const ushort*)&hh;
                const ushort* lp = (const ushort*)&hl;
                r0 = make_float4(bfr(hp[0]) + bfr(lp[0]), bfr(hp[1]) + bfr(lp[1]),
                                 bfr(hp[2]) + bfr(lp[2]), bfr(hp[3]) + bfr(lp[3]));
                r1 = make_float4(bfr(hp[4]) + bfr(lp[4]), bfr(hp[5]) + bfr(lp[5]),
                                 bfr(hp[6]) + bfr(lp[6]), bfr(hp[7]) + bfr(lp[7]));
            } else {
                r0 = make_float4(0.f, 0.f, 0.f, 0.f);
                r1 = r0;
            }
            *reinterpret_cast<float4*>(&Bs[bk][8 * fq])     = r0;
            *reinterpret_cast<float4*>(&Bs[bk][8 * fq + 4]) = r1;
        }
        __syncthreads();

        #pragma unroll
        for (int kk = 0; kk < TK; ++kk) {
            float4 av0 = *reinterpret_cast<const float4*>(&As[kk][8 * ty]);
            float4 av1 = *reinterpret_cast<const float4*>(&As[kk][8 * ty + 4]);
            float4 b0  = *reinterpret_cast<const float4*>(&Bs[kk][4 * tx]);
            float4 b1  = *reinterpret_cast<const float4*>(&Bs[kk][64 + 4 * tx]);
            const float a8[8] = {av0.x, av0.y, av0.z, av0.w, av1.x, av1.y, av1.z, av1.w};
            const float bw[8] = {b0.x, b0.y, b0.z, b0.w, b1.x, b1.y, b1.z, b1.w};
            #pragma unroll
            for (int i = 0; i < 8; ++i)
                #pragma unroll
                for (int j = 0; j < 8; ++j)
                    acc[i][j] = fmaf(a8[i], bw[j], acc[i][j]);
        }
        __syncthreads();
    }

    const float a1c = 1.0f - 0.9f, a9c = 0.9f;
    #pragma unroll
    for (int i = 0; i < 8; ++i) {
        const int n = n0 + 8 * ty + i;
        const ushort* hr = Hh + (size_t)n * SP;
        const ushort* lr = Hl + (size_t)n * SP;
        float* orow = out + (size_t)b * COUT * SP + (size_t)n * SP;
        {
            const int f = f0 + 4 * tx;
            ushort4 h4 = *(const ushort4*)&hr[f];
            ushort4 l4 = *(const ushort4*)&lr[f];
            float4 r = make_float4(
                a1c * acc[i][0] + a9c * (bfr(h4.x) + bfr(l4.x)),
                a1c * acc[i][1] + a9c * (bfr(h4.y) + bfr(l4.y)),
                a1c * acc[i][2] + a9c * (bfr(h4.z) + bfr(l4.z)),
                a1c * acc[i][3] + a9c * (bfr(h4.w) + bfr(l4.w)));
            *reinterpret_cast<float4*>(&orow[f]) = r;
        }
        if (f2ok) {
            const int f = f0 + 64 + 4 * tx;
            ushort4 h4 = *(const ushort4*)&hr[f];
            ushort4 l4 = *(const ushort4*)&lr[f];
            float4 r = make_float4(
                a1c * acc[i][4] + a9c * (bfr(h4.x) + bfr(l4.x)),
                a1c * acc[i][5] + a9c * (bfr(h4.y) + bfr(l4.y)),
                a1c * acc[i][6] + a9c * (bfr(h4.z) + bfr(l4.z)),
                a1c * acc[i][7] + a9c * (bfr(h4.w) + bfr(l4.w)));
            *reinterpret_cast<float4*>(&orow[f]) = r;
        }
    }
}

// ---------------------------------------------------------------------------
extern "C" void kernel_launch(void* const* d_in, const int* in_sizes, int n_in,
                              void* d_out, int out_size, void* d_ws, size_t ws_size,
                              hipStream_t stream)
{
    const float* x    = (const float*)d_in[0];
    const float* nn   = (const float*)d_in[1];
    const float* W    = (const float*)d_in[2];
    const float* bias = (const float*)d_in[3];
    float* out = (float*)d_out;

    // ws (111.2 MB): h1b_hi (51.4) | h1b_lo (51.4) | zone (8.39):
    //   conv phase: inT hi/lo (8 img, 6.89) + Wp hi/lo (0.59); gemm phase: attn f32.
    ushort* h1b_hi = (ushort*)d_ws;
    ushort* h1b_lo = h1b_hi + (size_t)NB * COUT * SP;
    char*   zone   = (char*)(h1b_lo + (size_t)NB * COUT * SP);
    ushort* inT_hi = (ushort*)zone;
    ushort* inT_lo = inT_hi + (size_t)8 * PD * PD * CIN;
    ushort* Wp_hi  = inT_lo + (size_t)8 * PD * PD * CIN;
    ushort* Wp_lo  = Wp_hi + 9 * 256 * 64;
    float*  attn   = (float*)zone;
    // d_out (102.8 MB): hnb_hi | hnb_lo until gemm_agg_k overwrites with out f32.
    ushort* hnb_hi = (ushort*)d_out;
    ushort* hnb_lo = hnb_hi + (size_t)NB * COUT * SP;

    pack_w<<<576, 256, 0, stream>>>(W, Wp_hi, Wp_lo);

    for (int c = 0; c < 8; ++c) {   // 4 chunks of x -> h1b, 4 chunks of n -> hnb
        const float* src = (c < 4) ? x  + (size_t)(8 * c)      * CIN * SP
                                   : nn + (size_t)(8 * c - 32) * CIN * SP;
        ushort* dh = (c < 4) ? h1b_hi + (size_t)(8 * c)      * COUT * SP
                             : hnb_hi + (size_t)(8 * c - 32) * COUT * SP;
        ushort* dl = (c < 4) ? h1b_lo + (size_t)(8 * c)      * COUT * SP
                             : hnb_lo + (size_t)(8 * c - 32) * COUT * SP;
        pack_in  <<<dim3(PD, 8),    256, 0, stream>>>(src, inT_hi, inT_lo);
        conv_mfma<<<dim3(2, 28, 8), 256, 0, stream>>>(inT_hi, inT_lo, Wp_hi, Wp_lo, bias, dh, dl);
    }

    gemm_a_mfma<<<dim3(32, 8),    256, 0, stream>>>(h1b_hi, h1b_lo, hnb_hi, hnb_lo, attn);
    softmax_k  <<<dim3(4, NB),    64,  0, stream>>>(attn);
    gemm_agg_k <<<dim3(25, 2, NB), 256, 0, stream>>>(attn, h1b_hi, h1b_lo, out);
}

// Round 10
// 636.577 us; speedup vs baseline: 1.9335x; 1.1059x over previous
//
#include <hip/hip_runtime.h>
#include <hip/hip_bf16.h>
#include <cstddef>

#define HH 56
#define WW 56
#define SP 3136          // 56*56
#define CIN 64
#define COUT 256
#define NB 32
#define NEG_SLOPE 0.01f
#define PD 58            // padded spatial dim (56 + 2 circular)

typedef __attribute__((ext_vector_type(8))) short short8v;  // 8 bf16 (4 VGPRs)
typedef __attribute__((ext_vector_type(4))) float f32x4;    // MFMA accumulator

__device__ __forceinline__ float bfr(ushort h) {
    union { uint u; float f; } c; c.u = ((uint)h) << 16; return c.f;
}
__device__ __forceinline__ void split_bf(float v, ushort& hi, ushort& lo) {
    __hip_bfloat16 h = __float2bfloat16(v);
    float r = v - __bfloat162float(h);
    __hip_bfloat16 l2 = __float2bfloat16(r);
    hi = *(ushort*)&h; lo = *(ushort*)&l2;
}

// ---------------------------------------------------------------------------
// pack_w: W[co][ci][ky][kx] f32 -> Wp_hi/Wp_lo[tap][co][ci] bf16 (hi + residual)
// ---------------------------------------------------------------------------
__global__ __launch_bounds__(256)
void pack_w(const float* __restrict__ W, ushort* __restrict__ wh, ushort* __restrict__ wl)
{
    const int id = blockIdx.x * 256 + threadIdx.x;   // 147456 = 9*256*64
    const int ci = id & 63, co = (id >> 6) & 255, tap = id >> 14;
    float v = W[(size_t)(co * 64 + ci) * 9 + tap];
    ushort hi, lo; split_bf(v, hi, lo);
    wh[id] = hi; wl[id] = lo;
}

// ---------------------------------------------------------------------------
// pack_in: raw[img][ci][y][x] f32 -> in_T[img][gy][gx][ci] bf16 hi/lo, with
// circular padding built in: in_T[gy][gx] = raw[(gy-1)%56][(gx-1)%56].
// ---------------------------------------------------------------------------
__global__ __launch_bounds__(256)
void pack_in(const float* __restrict__ src, ushort* __restrict__ th, ushort* __restrict__ tl)
{
    __shared__ float tile[CIN][PD];
    const int gy = blockIdx.x, img = blockIdx.y, tid = threadIdx.x;
    const int sy = (gy + 55) % 56;
    {
        const int ci = tid >> 2, seg = tid & 3;
        const float* s = src + (size_t)img * CIN * SP + (size_t)ci * SP + sy * 56;
        #pragma unroll
        for (int c = 0; c < 14; ++c) tile[ci][seg * 14 + c + 1] = s[seg * 14 + c];
    }
    if (tid < 128) {
        const int ci = tid >> 1;
        const float* s2 = src + (size_t)img * CIN * SP + (size_t)ci * SP + sy * 56;
        if (tid & 1) tile[ci][PD - 1] = s2[0];
        else         tile[ci][0]      = s2[55];
    }
    __syncthreads();
    const size_t ob = ((size_t)img * PD + gy) * PD * CIN;
    for (int el = tid; el < PD * CIN; el += 256) {
        const int gx = el >> 6, ci = el & 63;
        float v = tile[ci][gx];
        ushort hi, lo; split_bf(v, hi, lo);
        th[ob + el] = hi;     // el == gx*64 + ci
        tl[ob + el] = lo;
    }
}

// ---------------------------------------------------------------------------
// conv_mfma: implicit-GEMM 3x3 circular conv via bf16x3 MFMA. (unchanged)
// ---------------------------------------------------------------------------
__global__ __launch_bounds__(256, 2)
void conv_mfma(const ushort* __restrict__ inT_hi, const ushort* __restrict__ inT_lo,
               const ushort* __restrict__ Wp_hi, const ushort* __restrict__ Wp_lo,
               const float* __restrict__ bias,
               ushort* __restrict__ dsth, ushort* __restrict__ dstl)
{
    __shared__ __align__(16) ushort Ah[128][72];
    __shared__ __align__(16) ushort Al[128][72];
    __shared__ __align__(16) ushort Bh[112][72];
    __shared__ __align__(16) ushort Bl[112][72];
    const int tid = threadIdx.x;
    const int w = tid >> 6, l = tid & 63;
    const int co0 = blockIdx.x * 128;
    const int rp  = blockIdx.y;
    const int img = blockIdx.z;
    const int y0 = rp * 2, p0 = rp * 112;

    ushort* __restrict__ dh = dsth + (size_t)img * COUT * SP;
    ushort* __restrict__ dl = dstl + (size_t)img * COUT * SP;

    f32x4 acc[2][7];
    {
        const int rr = (l >> 4) * 4;
        #pragma unroll
        for (int m = 0; m < 2; ++m) {
            const int cb = co0 + 32 * w + 16 * m + rr;
            f32x4 bv = { bias[cb], bias[cb + 1], bias[cb + 2], bias[cb + 3] };
            #pragma unroll
            for (int nf = 0; nf < 7; ++nf) acc[m][nf] = bv;
        }
    }

    const int a_split = tid >> 7, a_row = tid & 127;
    const ushort* aW = a_split ? Wp_lo : Wp_hi;
    ushort (* __restrict__ aL)[72] = a_split ? Al : Ah;

    const int b_split = tid / 112;                // 0,1 active; 2 idle
    const int b_n = tid - b_split * 112;
    const int ry = (b_n >= 56) ? 1 : 0;
    const int xx = b_n - ry * 56;
    const ushort* bI = (b_split == 1) ? inT_lo : inT_hi;
    ushort (* __restrict__ bL)[72] = (b_split == 1) ? Bl : Bh;
    const bool bAct = tid < 224;

    for (int tap = 0; tap < 9; ++tap) {
        const int dy = tap / 3, dx = tap - dy * 3;
        {
            const uint4* g = (const uint4*)(aW + ((size_t)tap * 256 + co0 + a_row) * 64);
            uint4* d = (uint4*)&aL[a_row][0];
            #pragma unroll
            for (int j = 0; j < 8; ++j) d[j] = g[j];
        }
        if (bAct) {
            const int gy = y0 + ry + dy, gx = xx + dx;
            const uint4* g = (const uint4*)(bI + ((size_t)(img * PD + gy) * PD + gx) * 64);
            uint4* d = (uint4*)&bL[b_n][0];
            #pragma unroll
            for (int j = 0; j < 8; ++j) d[j] = g[j];
        }
        __syncthreads();
        #pragma unroll
        for (int ks = 0; ks < 2; ++ks) {
            const int kb = ks * 32 + (l >> 4) * 8;
            short8v ah[2], alv[2];
            #pragma unroll
            for (int m = 0; m < 2; ++m) {
                const int row = 32 * w + 16 * m + (l & 15);
                ah[m]  = *(const short8v*)&Ah[row][kb];
                alv[m] = *(const short8v*)&Al[row][kb];
            }
            #pragma unroll
            for (int nf = 0; nf < 7; ++nf) {
                const int brow = nf * 16 + (l & 15);
                short8v bh  = *(const short8v*)&Bh[brow][kb];
                short8v blv = *(const short8v*)&Bl[brow][kb];
                #pragma unroll
                for (int m = 0; m < 2; ++m) {
                    acc[m][nf] = __builtin_amdgcn_mfma_f32_16x16x32_bf16(ah[m],  bh,  acc[m][nf], 0, 0, 0);
                    acc[m][nf] = __builtin_amdgcn_mfma_f32_16x16x32_bf16(ah[m],  blv, acc[m][nf], 0, 0, 0);
                    acc[m][nf] = __builtin_amdgcn_mfma_f32_16x16x32_bf16(alv[m], bh,  acc[m][nf], 0, 0, 0);
                }
            }
        }
        __syncthreads();
    }

    const int rr = (l >> 4) * 4, cc = l & 15;
    #pragma unroll
    for (int m = 0; m < 2; ++m) {
        const int cb = co0 + 32 * w + 16 * m + rr;
        #pragma unroll
        for (int nf = 0; nf < 7; ++nf) {
            const int p = p0 + nf * 16 + cc;
            #pragma unroll
            for (int r = 0; r < 4; ++r) {
                ushort hi, lo; split_bf(acc[m][nf][r], hi, lo);
                dh[(size_t)(cb + r) * SP + p] = hi;
                dl[(size_t)(cb + r) * SP + p] = lo;
            }
        }
    }
}

// ---------------------------------------------------------------------------
// gemm_a_mfma: a[b][n][m] = LeakyReLU( sum_k h1[n,k]*hn[m,k] ), bf16x3. (unchanged)
// ---------------------------------------------------------------------------
__global__ __launch_bounds__(256)
void gemm_a_mfma(const ushort* __restrict__ h1h, const ushort* __restrict__ h1l,
                 const ushort* __restrict__ hnh, const ushort* __restrict__ hnl,
                 float* __restrict__ attn)
{
    __shared__ __align__(16) ushort Ah[128][72];
    __shared__ __align__(16) ushort Al[128][72];
    __shared__ __align__(16) ushort Bh[64][72];
    __shared__ __align__(16) ushort Bl[64][72];
    const int tid = threadIdx.x, w = tid >> 6, l = tid & 63;
    const int img = blockIdx.x, tile = blockIdx.y;
    const int n0 = (tile & 1) * 128, m0 = (tile >> 1) * 64;

    const ushort* __restrict__ Ahg = h1h + ((size_t)img * COUT + n0) * SP;
    const ushort* __restrict__ Alg = h1l + ((size_t)img * COUT + n0) * SP;
    const ushort* __restrict__ Bhg = hnh + ((size_t)img * COUT + m0) * SP;
    const ushort* __restrict__ Blg = hnl + ((size_t)img * COUT + m0) * SP;

    f32x4 acc[2][4];
    #pragma unroll
    for (int nf = 0; nf < 2; ++nf)
        #pragma unroll
        for (int mf = 0; mf < 4; ++mf) acc[nf][mf] = (f32x4){0.f, 0.f, 0.f, 0.f};

    const int arow = tid >> 1, ac = (tid & 1) * 32;
    const int brow = tid >> 2, bq = tid & 3;
    const int bpl = bq >> 1, bc = (bq & 1) * 32;
    const ushort* __restrict__ Bsrc = bpl ? Blg : Bhg;
    ushort (* __restrict__ Bdst)[72] = bpl ? Bl : Bh;

    for (int k0 = 0; k0 < SP; k0 += 64) {
        {
            const uint4* g0 = (const uint4*)(Ahg + (size_t)arow * SP + k0 + ac);
            const uint4* g1 = (const uint4*)(Alg + (size_t)arow * SP + k0 + ac);
            uint4* d0 = (uint4*)&Ah[arow][ac];
            uint4* d1 = (uint4*)&Al[arow][ac];
            #pragma unroll
            for (int j = 0; j < 4; ++j) { d0[j] = g0[j]; d1[j] = g1[j]; }
        }
        {
            const uint4* g = (const uint4*)(Bsrc + (size_t)brow * SP + k0 + bc);
            uint4* d = (uint4*)&Bdst[brow][bc];
            #pragma unroll
            for (int j = 0; j < 4; ++j) d[j] = g[j];
        }
        __syncthreads();
        #pragma unroll
        for (int ks = 0; ks < 2; ++ks) {
            const int kb = ks * 32 + (l >> 4) * 8;
            short8v ah[2], alv[2];
            #pragma unroll
            for (int nf = 0; nf < 2; ++nf) {
                const int row = 32 * w + 16 * nf + (l & 15);
                ah[nf]  = *(const short8v*)&Ah[row][kb];
                alv[nf] = *(const short8v*)&Al[row][kb];
            }
            #pragma unroll
            for (int mf = 0; mf < 4; ++mf) {
                const int br = mf * 16 + (l & 15);
                short8v bh  = *(const short8v*)&Bh[br][kb];
                short8v blv = *(const short8v*)&Bl[br][kb];
                #pragma unroll
                for (int nf = 0; nf < 2; ++nf) {
                    acc[nf][mf] = __builtin_amdgcn_mfma_f32_16x16x32_bf16(ah[nf],  bh,  acc[nf][mf], 0, 0, 0);
                    acc[nf][mf] = __builtin_amdgcn_mfma_f32_16x16x32_bf16(ah[nf],  blv, acc[nf][mf], 0, 0, 0);
                    acc[nf][mf] = __builtin_amdgcn_mfma_f32_16x16x32_bf16(alv[nf], bh,  acc[nf][mf], 0, 0, 0);
                }
            }
        }
        __syncthreads();
    }

    const int rr = (l >> 4) * 4, cc = l & 15;
    float* __restrict__ aimg = attn + (size_t)img * COUT * COUT;
    #pragma unroll
    for (int nf = 0; nf < 2; ++nf) {
        const int nb = n0 + 32 * w + 16 * nf + rr;
        #pragma unroll
        for (int mf = 0; mf < 4; ++mf) {
            const int m = m0 + 16 * mf + cc;
            #pragma unroll
            for (int r = 0; r < 4; ++r) {
                float v = acc[nf][mf][r];
                v = (v >= 0.f) ? v : NEG_SLOPE * v;
                aimg[(size_t)(nb + r) * COUT + m] = v;
            }
        }
    }
}

// ---------------------------------------------------------------------------
// softmax over axis n (dim=1) per (b,m) column, in place. (unchanged)
// ---------------------------------------------------------------------------
__global__ __launch_bounds__(64)
void softmax_k(float* __restrict__ attn)
{
    const int b = blockIdx.y;
    const int m = blockIdx.x * 64 + threadIdx.x;
    float* a = attn + (size_t)b * COUT * COUT;
    float mx = -1e30f;
    for (int n_ = 0; n_ < COUT; ++n_) mx = fmaxf(mx, a[n_ * COUT + m]);
    float s = 0.f;
    for (int n_ = 0; n_ < COUT; ++n_) s += expf(a[n_ * COUT + m] - mx);
    float inv = 1.f / s;
    for (int n_ = 0; n_ < COUT; ++n_)
        a[n_ * COUT + m] = expf(a[n_ * COUT + m] - mx) * inv;
}

// ---------------------------------------------------------------------------
// gemm_agg_mfma: out[n][f] = 0.1 * sum_m attn[n][m]*h1[m][f] + 0.9 * h1[n][f]
// bf16x3 MFMA. A = attn (f32, split hi/lo during staging, k=m contiguous).
// B = h1 hi/lo planes [m][f] -> LDS transpose-staged as [f][m].
// Tile 128n x 112f, K=256 in 64-chunks. Grid (28 f-tiles, 2 n-tiles, 32 img).
// Blend reads h1[n][f] post-MFMA (L2-hot: same rows just streamed as B).
// ---------------------------------------------------------------------------
__global__ __launch_bounds__(256, 2)
void gemm_agg_mfma(const float* __restrict__ attn,
                   const ushort* __restrict__ h1h, const ushort* __restrict__ h1l,
                   float* __restrict__ out)
{
    __shared__ __align__(16) ushort Ah[128][72];
    __shared__ __align__(16) ushort Al[128][72];
    __shared__ __align__(16) ushort Bh[112][72];
    __shared__ __align__(16) ushort Bl[112][72];
    const int tid = threadIdx.x, w = tid >> 6, l = tid & 63;
    const int f0 = blockIdx.x * 112;
    const int n0 = blockIdx.y * 128;
    const int img = blockIdx.z;

    const float*  __restrict__ A  = attn + (size_t)img * COUT * COUT;
    const ushort* __restrict__ Hh = h1h + (size_t)img * COUT * SP;
    const ushort* __restrict__ Hl = h1l + (size_t)img * COUT * SP;

    f32x4 acc[2][7];
    #pragma unroll
    for (int nf = 0; nf < 2; ++nf)
        #pragma unroll
        for (int mf = 0; mf < 7; ++mf) acc[nf][mf] = (f32x4){0.f, 0.f, 0.f, 0.f};

    // A staging: thread t -> row ar = t>>1, k-half ac = (t&1)*32
    const int ar = tid >> 1, ac = (tid & 1) * 32;
    // B staging: plane bp = t>>7; m-row bm = (t&127)>>1; f-seg bf = (t&1)*56
    const int bp = tid >> 7, bm = (tid & 127) >> 1, bf = (tid & 1) * 56;
    const ushort* __restrict__ Bsrc = bp ? Hl : Hh;
    ushort (* __restrict__ Bdst)[72] = bp ? Bl : Bh;

    for (int k0 = 0; k0 < COUT; k0 += 64) {
        {   // A: attn[n0+ar][k0+ac..+31] f32 -> split -> Ah/Al (packed b32 writes)
            const float* g = A + (size_t)(n0 + ar) * COUT + k0 + ac;
            uint* dh = (uint*)&Ah[ar][ac];
            uint* dl = (uint*)&Al[ar][ac];
            #pragma unroll
            for (int q = 0; q < 8; ++q) {
                float4 v = *(const float4*)(g + 4 * q);
                ushort h0, l0, h1_, l1_, h2, l2, h3, l3;
                split_bf(v.x, h0, l0); split_bf(v.y, h1_, l1_);
                split_bf(v.z, h2, l2); split_bf(v.w, h3, l3);
                dh[2 * q]     = (uint)h0 | ((uint)h1_ << 16);
                dh[2 * q + 1] = (uint)h2 | ((uint)h3  << 16);
                dl[2 * q]     = (uint)l0 | ((uint)l1_ << 16);
                dl[2 * q + 1] = (uint)l2 | ((uint)l3  << 16);
            }
        }
        {   // B: Bsrc[k0+bm][f0+bf..+55] -> transpose -> Bdst[f][bm]
            const ushort* g = Bsrc + (size_t)(k0 + bm) * SP + f0 + bf;
            #pragma unroll
            for (int q = 0; q < 7; ++q) {
                uint4 v = *(const uint4*)(g + 8 * q);     // 8 ushorts
                const ushort* vp = (const ushort*)&v;
                #pragma unroll
                for (int e = 0; e < 8; ++e)
                    Bdst[bf + 8 * q + e][bm] = vp[e];
            }
        }
        __syncthreads();
        #pragma unroll
        for (int ks = 0; ks < 2; ++ks) {
            const int kb = ks * 32 + (l >> 4) * 8;
            short8v ah[2], alv[2];
            #pragma unroll
            for (int nf = 0; nf < 2; ++nf) {
                const int row = 32 * w + 16 * nf + (l & 15);
                ah[nf]  = *(const short8v*)&Ah[row][kb];
                alv[nf] = *(const short8v*)&Al[row][kb];
            }
            #pragma unroll
            for (int mf = 0; mf < 7; ++mf) {
                const int br = mf * 16 + (l & 15);
                short8v bh  = *(const short8v*)&Bh[br][kb];
                short8v blv = *(const short8v*)&Bl[br][kb];
                #pragma unroll
                for (int nf = 0; nf < 2; ++nf) {
                    acc[nf][mf] = __builtin_amdgcn_mfma_f32_16x16x32_bf16(ah[nf],  bh,  acc[nf][mf], 0, 0, 0);
                    acc[nf][mf] = __builtin_amdgcn_mfma_f32_16x16x32_bf16(ah[nf],  blv, acc[nf][mf], 0, 0, 0);
                    acc[nf][mf] = __builtin_amdgcn_mfma_f32_16x16x32_bf16(alv[nf], bh,  acc[nf][mf], 0, 0, 0);
                }
            }
        }
        __syncthreads();
    }

    // epilogue: D row -> n, col -> f; fuse 0.1*agg + 0.9*h1 (hi+lo reconstruct)
    const int rr = (l >> 4) * 4, cc = l & 15;
    float* __restrict__ orow = out + (size_t)img * COUT * SP;
    #pragma unroll
    for (int nf = 0; nf < 2; ++nf) {
        const int nb = n0 + 32 * w + 16 * nf + rr;
        #pragma unroll
        for (int mf = 0; mf < 7; ++mf) {
            const int f = f0 + 16 * mf + cc;
            #pragma unroll
            for (int r = 0; r < 4; ++r) {
                const int n = nb + r;
                float h = bfr(Hh[(size_t)n * SP + f]) + bfr(Hl[(size_t)n * SP + f]);
                orow[(size_t)n * SP + f] = 0.1f * acc[nf][mf][r] + 0.9f * h;
            }
        }
    }
}

// ---------------------------------------------------------------------------
extern "C" void kernel_launch(void* const* d_in, const int* in_sizes, int n_in,
                              void* d_out, int out_size, void* d_ws, size_t ws_size,
                              hipStream_t stream)
{
    const float* x    = (const float*)d_in[0];
    const float* nn   = (const float*)d_in[1];
    const float* W    = (const float*)d_in[2];
    const float* bias = (const float*)d_in[3];
    float* out = (float*)d_out;

    // ws (111.2 MB): h1b_hi (51.4) | h1b_lo (51.4) | zone (8.39):
    //   conv phase: inT hi/lo (8 img, 6.89) + Wp hi/lo (0.59); gemm phase: attn f32.
    ushort* h1b_hi = (ushort*)d_ws;
    ushort* h1b_lo = h1b_hi + (size_t)NB * COUT * SP;
    char*   zone   = (char*)(h1b_lo + (size_t)NB * COUT * SP);
    ushort* inT_hi = (ushort*)zone;
    ushort* inT_lo = inT_hi + (size_t)8 * PD * PD * CIN;
    ushort* Wp_hi  = inT_lo + (size_t)8 * PD * PD * CIN;
    ushort* Wp_lo  = Wp_hi + 9 * 256 * 64;
    float*  attn   = (float*)zone;
    // d_out (102.8 MB): hnb_hi | hnb_lo until gemm_agg_mfma overwrites with out f32.
    ushort* hnb_hi = (ushort*)d_out;
    ushort* hnb_lo = hnb_hi + (size_t)NB * COUT * SP;

    pack_w<<<576, 256, 0, stream>>>(W, Wp_hi, Wp_lo);

    for (int c = 0; c < 8; ++c) {   // 4 chunks of x -> h1b, 4 chunks of n -> hnb
        const float* src = (c < 4) ? x  + (size_t)(8 * c)      * CIN * SP
                                   : nn + (size_t)(8 * c - 32) * CIN * SP;
        ushort* dh = (c < 4) ? h1b_hi + (size_t)(8 * c)      * COUT * SP
                             : hnb_hi + (size_t)(8 * c - 32) * COUT * SP;
        ushort* dl = (c < 4) ? h1b_lo + (size_t)(8 * c)      * COUT * SP
                             : hnb_lo + (size_t)(8 * c - 32) * COUT * SP;
        pack_in  <<<dim3(PD, 8),    256, 0, stream>>>(src, inT_hi, inT_lo);
        conv_mfma<<<dim3(2, 28, 8), 256, 0, stream>>>(inT_hi, inT_lo, Wp_hi, Wp_lo, bias, dh, dl);
    }

    gemm_a_mfma  <<<dim3(32, 8),     256, 0, stream>>>(h1b_hi, h1b_lo, hnb_hi, hnb_lo, attn);
    softmax_k    <<<dim3(4, NB),     64,  0, stream>>>(attn);
    gemm_agg_mfma<<<dim3(28, 2, NB), 256, 0, stream>>>(attn, h1b_hi, h1b_lo, out);
}